// Round 1
// baseline (104.907 us; speedup 1.0000x reference)
//
#include <hip/hip_runtime.h>
#include <hip/hip_cooperative_groups.h>
#include <math.h>

// Problem constants (reference: x [8,2,224,224] f32, weights [1,4] f32)
#define BATCH 8
#define CIN   2
#define H     224
#define W     224
#define NH    223
#define NW    223
#define PIXB  (H * W)          // floats per channel per batch = 50176
#define NPB   (CIN * H * W)    // floats per batch = 100352
#define PER_B (NH * NW)        // output positions per batch = 49729
#define GBX   64               // blocks per batch (grid.x)
#define N4    (NPB / 4)        // 25088 float4 per batch
#define PERBLK (N4 / GBX)      // 392 float4 per block in phase 1
#define PI_F  3.14159265358979323846f

namespace cg = cooperative_groups;

// Fused kernel, cooperative launch, grid (GBX, BATCH) x 256 threads = 512 blocks
// (2 blocks/CU -> always co-resident; cooperative occupancy check is safe).
//
// Phase 1: each block reduces its 392-float4 slice of batch b -> partial
//          min/max in ws[b*GBX+cb] / ws[BATCH*GBX + b*GBX + cb].
// grid.sync()
// Phase 2: each block re-reduces batch b's 64 partials with one wave (cheap,
//          L2-hit), then grid-strides over output positions computing the
//          analytic 4-qubit circuit:
//          z_q = cos(a_q) cos(b_q) cos(w_q) - sin(a_q) sin(w_q)
//          out[b,0]=z1 z2 z3; out[b,1]=z0 z1; out[b,2]=z0 z1 z2; out[b,3]=z0 z1 z2 z3
__global__ __launch_bounds__(256) void fused_quanv(
        const float* __restrict__ x, const float* __restrict__ wts,
        float* __restrict__ ws, float* __restrict__ out) {
    const int b  = blockIdx.y;
    const int cb = blockIdx.x;

    // ---------------- Phase 1: partial min/max ----------------
    const float4* xb = (const float4*)(x + (size_t)b * NPB);
    float lmin =  INFINITY, lmax = -INFINITY;
    for (int idx = cb * PERBLK + threadIdx.x; idx < (cb + 1) * PERBLK; idx += 256) {
        float4 v = xb[idx];
        lmin = fminf(lmin, fminf(fminf(v.x, v.y), fminf(v.z, v.w)));
        lmax = fmaxf(lmax, fmaxf(fmaxf(v.x, v.y), fmaxf(v.z, v.w)));
    }
    #pragma unroll
    for (int off = 32; off > 0; off >>= 1) {
        lmin = fminf(lmin, __shfl_down(lmin, off, 64));
        lmax = fmaxf(lmax, __shfl_down(lmax, off, 64));
    }
    __shared__ float smin[4], smax[4];
    const int wid = threadIdx.x >> 6;
    if ((threadIdx.x & 63) == 0) { smin[wid] = lmin; smax[wid] = lmax; }
    __syncthreads();
    if (threadIdx.x == 0) {
        #pragma unroll
        for (int i = 1; i < 4; ++i) {
            lmin = fminf(lmin, smin[i]);
            lmax = fmaxf(lmax, smax[i]);
        }
        ws[b * GBX + cb]               = lmin;
        ws[BATCH * GBX + b * GBX + cb] = lmax;
    }

    cg::this_grid().sync();

    // ---------------- Phase 2: final reduce + circuit ----------------
    __shared__ float sred[2];
    if (threadIdx.x < GBX) {   // GBX == 64: one wave
        float mn = ws[b * GBX + threadIdx.x];
        float mx = ws[BATCH * GBX + b * GBX + threadIdx.x];
        #pragma unroll
        for (int off = 32; off > 0; off >>= 1) {
            mn = fminf(mn, __shfl_down(mn, off, 64));
            mx = fmaxf(mx, __shfl_down(mx, off, 64));
        }
        if (threadIdx.x == 0) { sred[0] = mn; sred[1] = mx; }
    }
    __syncthreads();
    const float gmin  = sred[0];
    const float scale = PI_F / (sred[1] - gmin + 1e-8f);

    // Weight sincos hoisted out of the position loop (uniform, cache-broadcast)
    float sw[4], cw[4];
    #pragma unroll
    for (int q = 0; q < 4; ++q) __sincosf(wts[q], &sw[q], &cw[q]);

    const float* xbase = x + (size_t)b * NPB;
    const size_t obase = (size_t)b * 4 * PER_B;

    for (int r = cb * 256 + threadIdx.x; r < PER_B; r += GBX * 256) {
        int i = r / NW;
        int j = r - i * NW;
        const float* c0 = xbase + i * W + j;
        const float* c1 = c0 + PIXB;

        float z[4];
        #pragma unroll
        for (int q = 0; q < 4; ++q) {
            int kh = q >> 1, kw = q & 1;
            float a  = (c0[kh * W + kw] - gmin) * scale;   // channel 0 -> RX
            float bb = (c1[kh * W + kw] - gmin) * scale;   // channel 1 -> RY
            float sa, ca;
            __sincosf(a, &sa, &ca);
            float cb2 = __cosf(bb);
            z[q] = ca * cb2 * cw[q] - sa * sw[q];
        }

        float z01 = z[0] * z[1];
        out[obase + r]             = z[1] * z[2] * z[3];
        out[obase + PER_B + r]     = z01;
        out[obase + 2 * PER_B + r] = z01 * z[2];
        out[obase + 3 * PER_B + r] = z01 * z[2] * z[3];
    }
}

// ---- Fallback path (old two-kernel structure) in case cooperative launch
// ---- is rejected; kept bit-identical to the verified baseline.
#define BPB   32
#define NBPB  ((PER_B + 255) / 256)

__global__ __launch_bounds__(256) void minmax_kernel(
        const float* __restrict__ x, float* __restrict__ ws) {
    int b  = blockIdx.x / BPB;
    int cb = blockIdx.x % BPB;
    const float4* xb = (const float4*)(x + (size_t)b * NPB);
    const int per = (NPB / 4) / BPB;
    float lmin =  INFINITY, lmax = -INFINITY;
    for (int idx = cb * per + threadIdx.x; idx < (cb + 1) * per; idx += 256) {
        float4 v = xb[idx];
        lmin = fminf(lmin, fminf(fminf(v.x, v.y), fminf(v.z, v.w)));
        lmax = fmaxf(lmax, fmaxf(fmaxf(v.x, v.y), fmaxf(v.z, v.w)));
    }
    #pragma unroll
    for (int off = 32; off > 0; off >>= 1) {
        lmin = fminf(lmin, __shfl_down(lmin, off, 64));
        lmax = fmaxf(lmax, __shfl_down(lmax, off, 64));
    }
    __shared__ float smin[4], smax[4];
    int wid = threadIdx.x >> 6;
    if ((threadIdx.x & 63) == 0) { smin[wid] = lmin; smax[wid] = lmax; }
    __syncthreads();
    if (threadIdx.x == 0) {
        #pragma unroll
        for (int i = 1; i < 4; ++i) {
            lmin = fminf(lmin, smin[i]);
            lmax = fmaxf(lmax, smax[i]);
        }
        ws[b * BPB + cb]       = lmin;
        ws[256 + b * BPB + cb] = lmax;
    }
}

__global__ __launch_bounds__(256) void quanv_kernel(
        const float* __restrict__ x, const float* __restrict__ wts,
        const float* __restrict__ ws, float* __restrict__ out) {
    int b = blockIdx.y;
    __shared__ float sred[2];
    if (threadIdx.x < 32) {
        float mn = ws[b * BPB + threadIdx.x];
        float mx = ws[256 + b * BPB + threadIdx.x];
        #pragma unroll
        for (int off = 16; off > 0; off >>= 1) {
            mn = fminf(mn, __shfl_xor(mn, off, 32));
            mx = fmaxf(mx, __shfl_xor(mx, off, 32));
        }
        if (threadIdx.x == 0) { sred[0] = mn; sred[1] = mx; }
    }
    __syncthreads();
    float gmin  = sred[0];
    float scale = PI_F / (sred[1] - gmin + 1e-8f);

    int r = blockIdx.x * 256 + threadIdx.x;
    if (r >= PER_B) return;
    int i = r / NW;
    int j = r - i * NW;

    const float* c0 = x + (size_t)b * NPB + (size_t)i * W + j;
    const float* c1 = c0 + PIXB;

    float z[4];
    #pragma unroll
    for (int q = 0; q < 4; ++q) {
        int kh = q >> 1, kw = q & 1;
        float pa = c0[kh * W + kw];
        float pb = c1[kh * W + kw];
        float a  = (pa - gmin) * scale;
        float bb = (pb - gmin) * scale;
        float sa, ca;
        __sincosf(a, &sa, &ca);
        float cb = __cosf(bb);
        float sw, cwv;
        __sincosf(wts[q], &sw, &cwv);
        z[q] = ca * cb * cwv - sa * sw;
    }

    size_t base = (size_t)b * 4 * PER_B + r;
    float z01 = z[0] * z[1];
    out[base]             = z[1] * z[2] * z[3];
    out[base + PER_B]     = z01;
    out[base + 2 * PER_B] = z01 * z[2];
    out[base + 3 * PER_B] = z01 * z[2] * z[3];
}

extern "C" void kernel_launch(void* const* d_in, const int* in_sizes, int n_in,
                              void* d_out, int out_size, void* d_ws, size_t ws_size,
                              hipStream_t stream) {
    const float* x   = (const float*)d_in[0];   // [8,2,224,224] f32
    const float* wts = (const float*)d_in[1];   // [1,4] f32
    float* out = (float*)d_out;                 // [8,4,223,223] f32
    float* ws  = (float*)d_ws;

    void* args[] = { (void*)&x, (void*)&wts, (void*)&ws, (void*)&out };
    dim3 grid(GBX, BATCH), block(256, 1, 1);
    hipError_t err = hipLaunchCooperativeKernel(
        (const void*)fused_quanv, grid, block, args, 0, stream);
    if (err != hipSuccess) {
        // Fallback: verified two-kernel baseline
        minmax_kernel<<<BATCH * BPB, 256, 0, stream>>>(x, ws);
        quanv_kernel<<<dim3(NBPB, BATCH), 256, 0, stream>>>(x, wts, ws, out);
    }
}

// Round 2
// 62.513 us; speedup vs baseline: 1.6782x; 1.6782x over previous
//
#include <hip/hip_runtime.h>
#include <math.h>

// Problem constants (reference: x [8,2,224,224] f32, weights [1,4] f32)
#define BATCH 8
#define CIN   2
#define H     224
#define W     224
#define NH    223
#define NW    223
#define PIXB  (H * W)          // floats per channel per batch = 50176
#define NPB   (CIN * H * W)    // floats per batch = 100352
#define PER_B (NH * NW)        // output positions per batch = 49729
#define BPB   32               // reduction blocks per batch
#define TPR   56               // thread-slots per output row (4 positions each)
#define SLOTS (NH * TPR)       // 12488 slots per batch
#define QBLK  ((SLOTS + 255) / 256)   // 49 blocks per batch
#define PI_F  3.14159265358979323846f

// ws layout: [0..255]   per-block min (b*32+cb)
//            [256..511] per-block max
//            [512..515] sin(wts[q]); [516..519] cos(wts[q])

// Kernel 1: per-block partial min/max (32 blocks/batch, 256 thr) + weight trig.
__global__ __launch_bounds__(256) void minmax_kernel(
        const float* __restrict__ x, const float* __restrict__ wts,
        float* __restrict__ ws) {
    // One-off: weight sincos, computed by block 0 while others reduce.
    if (blockIdx.x == 0 && threadIdx.x < 4) {
        float s, c;
        __sincosf(wts[threadIdx.x], &s, &c);
        ws[512 + threadIdx.x] = s;
        ws[516 + threadIdx.x] = c;
    }
    int b  = blockIdx.x / BPB;
    int cb = blockIdx.x % BPB;
    const float4* xb = (const float4*)(x + (size_t)b * NPB);
    const int per = (NPB / 4) / BPB;     // 784 float4 per block
    float lmin =  INFINITY, lmax = -INFINITY;
    for (int idx = cb * per + threadIdx.x; idx < (cb + 1) * per; idx += 256) {
        float4 v = xb[idx];
        lmin = fminf(lmin, fminf(fminf(v.x, v.y), fminf(v.z, v.w)));
        lmax = fmaxf(lmax, fmaxf(fmaxf(v.x, v.y), fmaxf(v.z, v.w)));
    }
    #pragma unroll
    for (int off = 32; off > 0; off >>= 1) {
        lmin = fminf(lmin, __shfl_down(lmin, off, 64));
        lmax = fmaxf(lmax, __shfl_down(lmax, off, 64));
    }
    __shared__ float smin[4], smax[4];
    int wid = threadIdx.x >> 6;
    if ((threadIdx.x & 63) == 0) { smin[wid] = lmin; smax[wid] = lmax; }
    __syncthreads();
    if (threadIdx.x == 0) {
        #pragma unroll
        for (int i = 1; i < 4; ++i) {
            lmin = fminf(lmin, smin[i]);
            lmax = fmaxf(lmax, smax[i]);
        }
        ws[b * BPB + cb]       = lmin;
        ws[256 + b * BPB + cb] = lmax;
    }
}

// Kernel 2: analytic 4-qubit circuit, 4 consecutive output positions/thread.
// z_q = cos(a_q) cos(b_q) cos(w_q) - sin(a_q) sin(w_q)
// Positions jt..jt+3 of row i need ch0/ch1 pixels rows i,i+1 cols jt..jt+4:
// shared trig across the 4 positions (30 trans values vs 48 + 32 for weights).
__global__ __launch_bounds__(256) void quanv_kernel(
        const float* __restrict__ x, const float* __restrict__ ws,
        float* __restrict__ out) {
    const int b = blockIdx.y;
    __shared__ float sred[2];
    if (threadIdx.x < 32) {
        float mn = ws[b * BPB + threadIdx.x];
        float mx = ws[256 + b * BPB + threadIdx.x];
        #pragma unroll
        for (int off = 16; off > 0; off >>= 1) {
            mn = fminf(mn, __shfl_xor(mn, off, 32));
            mx = fmaxf(mx, __shfl_xor(mx, off, 32));
        }
        if (threadIdx.x == 0) { sred[0] = mn; sred[1] = mx; }
    }
    __syncthreads();
    const float gmin  = sred[0];
    const float scale = PI_F / (sred[1] - gmin + 1e-8f);

    // Precomputed weight trig: uniform address -> scalar loads, L2-hit.
    const float sw0 = ws[512], sw1 = ws[513], sw2 = ws[514], sw3 = ws[515];
    const float cw0 = ws[516], cw1 = ws[517], cw2 = ws[518], cw3 = ws[519];

    int slot = blockIdx.x * 256 + threadIdx.x;
    if (slot >= SLOTS) return;
    int i  = slot / TPR;
    int jt = (slot - i * TPR) * 4;            // 0,4,...,220
    const int npos = (jt == 220) ? 3 : 4;     // last slot covers 3 positions

    // Aligned float4 loads: W=224 (mult of 4), jt mult of 4, PIXB mult of 4.
    const float* r0 = x + (size_t)b * NPB + i * W + jt;   // ch0 row i
    const float* r1 = r0 + W;                             // ch0 row i+1
    const float* r2 = r0 + PIXB;                          // ch1 row i
    const float* r3 = r2 + W;                             // ch1 row i+1
    float4 v0 = *(const float4*)r0;
    float4 v1 = *(const float4*)r1;
    float4 v2 = *(const float4*)r2;
    float4 v3 = *(const float4*)r3;
    float e0 = 0.f, e1 = 0.f, e2 = 0.f, e3 = 0.f;
    if (jt < 220) { e0 = r0[4]; e1 = r1[4]; e2 = r2[4]; e3 = r3[4]; }

    const float p0[5] = {v0.x, v0.y, v0.z, v0.w, e0};   // ch0 row i
    const float p1[5] = {v1.x, v1.y, v1.z, v1.w, e1};   // ch0 row i+1
    const float p2[5] = {v2.x, v2.y, v2.z, v2.w, e2};   // ch1 row i
    const float p3[5] = {v3.x, v3.y, v3.z, v3.w, e3};   // ch1 row i+1

    float sa0[5], ca0[5], sa1[5], ca1[5], cb0[5], cb1[5];
    #pragma unroll
    for (int k = 0; k < 5; ++k) {
        __sincosf((p0[k] - gmin) * scale, &sa0[k], &ca0[k]);
        __sincosf((p1[k] - gmin) * scale, &sa1[k], &ca1[k]);
        cb0[k] = __cosf((p2[k] - gmin) * scale);
        cb1[k] = __cosf((p3[k] - gmin) * scale);
    }

    const size_t obase = (size_t)b * 4 * PER_B + (size_t)i * NW + jt;
    #pragma unroll
    for (int p = 0; p < 4; ++p) {
        if (p < npos) {
            // q0=(0,0) q1=(0,1) q2=(1,0) q3=(1,1); a from ch0, b from ch1
            float z0 = ca0[p]     * cb0[p]     * cw0 - sa0[p]     * sw0;
            float z1 = ca0[p + 1] * cb0[p + 1] * cw1 - sa0[p + 1] * sw1;
            float z2 = ca1[p]     * cb1[p]     * cw2 - sa1[p]     * sw2;
            float z3 = ca1[p + 1] * cb1[p + 1] * cw3 - sa1[p + 1] * sw3;
            float z01 = z0 * z1;
            out[obase + p]             = z1 * z2 * z3;
            out[obase + PER_B + p]     = z01;
            out[obase + 2 * PER_B + p] = z01 * z2;
            out[obase + 3 * PER_B + p] = z01 * z2 * z3;
        }
    }
}

extern "C" void kernel_launch(void* const* d_in, const int* in_sizes, int n_in,
                              void* d_out, int out_size, void* d_ws, size_t ws_size,
                              hipStream_t stream) {
    const float* x   = (const float*)d_in[0];   // [8,2,224,224] f32
    const float* wts = (const float*)d_in[1];   // [1,4] f32
    float* out = (float*)d_out;                 // [8,4,223,223] f32
    float* ws  = (float*)d_ws;

    minmax_kernel<<<BATCH * BPB, 256, 0, stream>>>(x, wts, ws);
    quanv_kernel<<<dim3(QBLK, BATCH), 256, 0, stream>>>(x, ws, out);
}